// Round 1
// baseline (12238.129 us; speedup 1.0000x reference)
//
#include <hip/hip_runtime.h>

typedef _Float16 half8 __attribute__((ext_vector_type(8)));
typedef _Float16 half4v __attribute__((ext_vector_type(4)));
typedef float f32x4 __attribute__((ext_vector_type(4)));

#define T_LEN 2048
#define BSZ   64
#define INSZ  256
#define HSZ   512
#define G4H   2048

// workspace layout (bytes)
#define OFF_XW   0ULL           // [2048][64][2048] fp16 = 536,870,912
#define OFF_X16  536870912ULL   // [131072][256] fp16   =  67,108,864
#define OFF_WIT  603979776ULL   // [2048][256] fp16     =   1,048,576
#define OFF_WHT  605028352ULL   // [2048][512] fp16     =   2,097,152
#define OFF_HBUF 607125504ULL   // [2][64][512] fp16    =     131,072
#define OFF_CTR  607256576ULL   // 4 counters, 128B apart

__device__ __forceinline__ float fast_rcp(float x) { return __builtin_amdgcn_rcpf(x); }
__device__ __forceinline__ float sigm(float x)  { return fast_rcp(1.f + __expf(-x)); }
__device__ __forceinline__ float tanhf_(float x){ return 1.f - 2.f * fast_rcp(1.f + __expf(2.f * x)); }

// ---------- phase 0: converts / transposes / init ----------
__global__ void convert_x(const float* __restrict__ x, _Float16* __restrict__ x16, int n4) {
    int i = blockIdx.x * blockDim.x + threadIdx.x;
    int stride = gridDim.x * blockDim.x;
    const float4* xv = (const float4*)x;
    for (; i < n4; i += stride) {
        float4 v = xv[i];
        half4v h;
        h[0] = (_Float16)v.x; h[1] = (_Float16)v.y;
        h[2] = (_Float16)v.z; h[3] = (_Float16)v.w;
        *(half4v*)(x16 + (size_t)i * 4) = h;
    }
}

// W[K][N] (N=2048) -> WT[N][K], fp32 -> fp16
__global__ void transpose_w(const float* __restrict__ W, _Float16* __restrict__ WT, int K) {
    int id = blockIdx.x * blockDim.x + threadIdx.x;
    int total = K * G4H, stride = gridDim.x * blockDim.x;
    for (; id < total; id += stride) {
        int k = id >> 11;         // /2048
        int n = id & 2047;
        WT[(size_t)n * K + k] = (_Float16)W[id];  // coalesced read over n
    }
}

__global__ void init_state(unsigned* __restrict__ hbuf_u, unsigned* __restrict__ ctr) {
    int id = blockIdx.x * blockDim.x + threadIdx.x;
    if (id < 32768) hbuf_u[id] = 0u;   // zero both h buffers (2*64*512 fp16 = 32768 u32)
    if (id < 128)   ctr[id] = 0u;
}

// ---------- phase 1: xW = x16 @ Wi + (bias in epilogue), fp16 out ----------
// A = x16 [131072,256], Bt = WiT [2048,256], C = xW [131072,2048]
__global__ __launch_bounds__(256) void gemm_xw(const _Float16* __restrict__ A,
                                               const _Float16* __restrict__ Bt,
                                               const float* __restrict__ bias,
                                               _Float16* __restrict__ C) {
    __shared__ __align__(16) _Float16 As[128 * 32];
    __shared__ __align__(16) _Float16 Bs[128 * 32];
    const int tid  = threadIdx.x;
    const int w    = tid >> 6;
    const int l    = tid & 63;
    const int lo   = l & 15;
    const int quad = l >> 4;
    const int rowBase = blockIdx.y * 128;
    const int colBase = blockIdx.x * 128;
    const int wr = (w >> 1) * 64, wc = (w & 1) * 64;

    f32x4 acc[4][4] = {};

    const int v0 = tid, v1 = tid + 256;   // vec ids: row = v>>2, kcol = (v&3)*8
    for (int kt = 0; kt < 8; kt++) {
        ((half8*)As)[v0] = *(const half8*)(A + (size_t)(rowBase + (v0 >> 2)) * INSZ + kt * 32 + (v0 & 3) * 8);
        ((half8*)As)[v1] = *(const half8*)(A + (size_t)(rowBase + (v1 >> 2)) * INSZ + kt * 32 + (v1 & 3) * 8);
        ((half8*)Bs)[v0] = *(const half8*)(Bt + (size_t)(colBase + (v0 >> 2)) * INSZ + kt * 32 + (v0 & 3) * 8);
        ((half8*)Bs)[v1] = *(const half8*)(Bt + (size_t)(colBase + (v1 >> 2)) * INSZ + kt * 32 + (v1 & 3) * 8);
        __syncthreads();
        half8 af[4], bf[4];
#pragma unroll
        for (int mt = 0; mt < 4; mt++)
            af[mt] = *(const half8*)(As + (wr + mt * 16 + lo) * 32 + quad * 8);
#pragma unroll
        for (int nt = 0; nt < 4; nt++)
            bf[nt] = *(const half8*)(Bs + (wc + nt * 16 + lo) * 32 + quad * 8);
#pragma unroll
        for (int mt = 0; mt < 4; mt++)
#pragma unroll
            for (int nt = 0; nt < 4; nt++)
                acc[mt][nt] = __builtin_amdgcn_mfma_f32_16x16x32_f16(af[mt], bf[nt], acc[mt][nt], 0, 0, 0);
        __syncthreads();
    }

#pragma unroll
    for (int nt = 0; nt < 4; nt++) {
        int col = colBase + wc + nt * 16 + lo;
        float bv = bias[col];
#pragma unroll
        for (int mt = 0; mt < 4; mt++) {
#pragma unroll
            for (int r = 0; r < 4; r++) {
                int row = rowBase + wr + mt * 16 + quad * 4 + r;
                C[(size_t)row * G4H + col] = (_Float16)(acc[mt][nt][r] + bv);
            }
        }
    }
}

// ---------- phase 2: persistent recurrent scan ----------
// 32 blocks = 4 sample-groups (16 samples) x 8 col-blocks (64 h-cols).
// Wh fragments register-resident across all timesteps; per-group atomic barrier.
#define CBLK 8
__global__ __launch_bounds__(256, 1) void lstm_scan(const _Float16* __restrict__ xw,   // [T][64][2048]
                                                    const _Float16* __restrict__ whT,  // [2048][512]
                                                    _Float16* __restrict__ hbuf,       // [2][64][512]
                                                    unsigned* __restrict__ ctr,
                                                    float* __restrict__ out) {
    const int tid  = threadIdx.x;
    const int w    = tid >> 6;
    const int l    = tid & 63;
    const int lo   = l & 15;
    const int quad = l >> 4;
    // group on 2 XCDs under round-robin blockIdx%8 mapping (perf heuristic only)
    const int g = blockIdx.x & 3;
    const int j = blockIdx.x >> 2;
    const int col = j * 64 + w * 16 + lo;   // h column (B n-index / C col)
    const int sr0 = quad * 4;               // C-layout sample-row base
    const int bglob = g * 16;               // first sample of group

    // persistent Wh fragments: bfrag[q][kt], n = q*512+col, k = kt*32 + quad*8 + j'
    half8 bfrag[4][16];
#pragma unroll
    for (int q = 0; q < 4; q++) {
        const _Float16* wrow = whT + (size_t)(q * HSZ + col) * HSZ + quad * 8;
#pragma unroll
        for (int kt = 0; kt < 16; kt++)
            bfrag[q][kt] = *(const half8*)(wrow + kt * 32);
    }

    float creg[4] = {0.f, 0.f, 0.f, 0.f};

    // prefetch xW for t=0
    float xpre[4][4];
#pragma unroll
    for (int q = 0; q < 4; q++)
#pragma unroll
        for (int r = 0; r < 4; r++)
            xpre[q][r] = (float)xw[(size_t)(bglob + sr0 + r) * G4H + q * HSZ + col];

    unsigned* myctr = ctr + g * 32;

    for (int t = 0; t < T_LEN; t++) {
        const int rb = t & 1, wb = rb ^ 1;

        // A fragments: h_prev[m=lo][k], issued as 16 pipelined dwordx4 loads
        const _Float16* hrow = hbuf + rb * (BSZ * HSZ) + (size_t)(bglob + lo) * HSZ + quad * 8;
        half8 af[16];
#pragma unroll
        for (int kt = 0; kt < 16; kt++) af[kt] = *(const half8*)(hrow + kt * 32);

        f32x4 acc[4];
#pragma unroll
        for (int q = 0; q < 4; q++) {
            acc[q][0] = xpre[q][0]; acc[q][1] = xpre[q][1];
            acc[q][2] = xpre[q][2]; acc[q][3] = xpre[q][3];
        }
#pragma unroll
        for (int kt = 0; kt < 16; kt++)
#pragma unroll
            for (int q = 0; q < 4; q++)
                acc[q] = __builtin_amdgcn_mfma_f32_16x16x32_f16(af[kt], bfrag[q][kt], acc[q], 0, 0, 0);

        // prefetch next step's xW (independent of recurrence; overlaps MFMA drain)
        if (t + 1 < T_LEN) {
#pragma unroll
            for (int q = 0; q < 4; q++)
#pragma unroll
                for (int r = 0; r < 4; r++)
                    xpre[q][r] = (float)xw[((size_t)(t + 1) * BSZ + bglob + sr0 + r) * G4H + q * HSZ + col];
        }

        // epilogue: gates -> c,h (lane-local; C-layout row = quad*4+r, col = lo-based)
#pragma unroll
        for (int r = 0; r < 4; r++) {
            float iv = sigm(acc[0][r]);
            float fv = sigm(acc[1][r]);
            float gv = tanhf_(acc[2][r]);
            float ov = sigm(acc[3][r]);
            float cn = fv * creg[r] + iv * gv;
            creg[r] = cn;
            float hn = ov * tanhf_(cn);
            const size_t brow = (size_t)(bglob + sr0 + r);
            hbuf[wb * (BSZ * HSZ) + brow * HSZ + col] = (_Float16)hn;
            out[((size_t)t * BSZ + brow) * HSZ + col] = hn;
            if (t == T_LEN - 1) {
                out[(size_t)T_LEN * BSZ * HSZ + brow * HSZ + col] = hn;                 // hT
                out[(size_t)T_LEN * BSZ * HSZ + (size_t)BSZ * HSZ + brow * HSZ + col] = cn; // cT
            }
        }

        // inter-block barrier (group-local). __syncthreads drains all waves' stores
        // (compiler emits vmcnt(0) before s_barrier); tid0 release-fence (buffer_wbl2)
        // makes h visible at the coherent point for other XCDs, then arrive+spin.
        __syncthreads();
        if (tid == 0) {
            __threadfence();  // release
            __hip_atomic_fetch_add(myctr, 1u, __ATOMIC_RELAXED, __HIP_MEMORY_SCOPE_AGENT);
            const unsigned target = (unsigned)(CBLK * (t + 1));
            while (__hip_atomic_load(myctr, __ATOMIC_RELAXED, __HIP_MEMORY_SCOPE_AGENT) < target)
                __builtin_amdgcn_s_sleep(1);
            __threadfence();  // acquire: invalidate L1/L2 so fresh h is re-fetched
        }
        __syncthreads();
    }
}

extern "C" void kernel_launch(void* const* d_in, const int* in_sizes, int n_in,
                              void* d_out, int out_size, void* d_ws, size_t ws_size,
                              hipStream_t stream) {
    const float* x  = (const float*)d_in[0];   // [2048,64,256]
    const float* Wi = (const float*)d_in[1];   // [256,2048]
    const float* Wh = (const float*)d_in[2];   // [512,2048]
    const float* B  = (const float*)d_in[3];   // [2048]
    float* out = (float*)d_out;

    char* ws = (char*)d_ws;
    _Float16* xW   = (_Float16*)(ws + OFF_XW);
    _Float16* x16  = (_Float16*)(ws + OFF_X16);
    _Float16* WiT  = (_Float16*)(ws + OFF_WIT);
    _Float16* WhT  = (_Float16*)(ws + OFF_WHT);
    _Float16* hbuf = (_Float16*)(ws + OFF_HBUF);
    unsigned* ctr  = (unsigned*)(ws + OFF_CTR);

    hipLaunchKernelGGL(convert_x, dim3(4096), dim3(256), 0, stream, x, x16, 8388608);
    hipLaunchKernelGGL(transpose_w, dim3(512), dim3(256), 0, stream, Wi, WiT, INSZ);
    hipLaunchKernelGGL(transpose_w, dim3(1024), dim3(256), 0, stream, Wh, WhT, HSZ);
    hipLaunchKernelGGL(init_state, dim3(128), dim3(256), 0, stream, (unsigned*)hbuf, ctr);
    hipLaunchKernelGGL(gemm_xw, dim3(16, 1024), dim3(256), 0, stream, x16, WiT, B, xW);
    hipLaunchKernelGGL(lstm_scan, dim3(32), dim3(256), 0, stream, xW, WhT, hbuf, ctr, out);
}

// Round 2
// 10983.889 us; speedup vs baseline: 1.1142x; 1.1142x over previous
//
#include <hip/hip_runtime.h>

typedef _Float16 half8 __attribute__((ext_vector_type(8)));
typedef _Float16 half4v __attribute__((ext_vector_type(4)));
typedef float f32x4 __attribute__((ext_vector_type(4)));

#define T_LEN 2048
#define BSZ   64
#define INSZ  256
#define HSZ   512
#define G4H   2048

// workspace layout (bytes)
#define OFF_XW   0ULL           // [2048][64][2048] fp16 = 536,870,912
#define OFF_X16  536870912ULL   // [131072][256] fp16   =  67,108,864
#define OFF_WIT  603979776ULL   // [2048][256] fp16     =   1,048,576
#define OFF_WHT  605028352ULL   // [2048][512] fp16     =   2,097,152
#define OFF_HBUF 607125504ULL   // [2][64][512] fp16    =     131,072
#define OFF_CTR  607256576ULL   // 4 counters, 128B apart

__device__ __forceinline__ float fast_rcp(float x) { return __builtin_amdgcn_rcpf(x); }
__device__ __forceinline__ float sigm(float x)  { return fast_rcp(1.f + __expf(-x)); }
__device__ __forceinline__ float tanhf_(float x){ return 1.f - 2.f * fast_rcp(1.f + __expf(2.f * x)); }

// ---------- phase 0: converts / transposes / init ----------
__global__ void convert_x(const float* __restrict__ x, _Float16* __restrict__ x16, int n4) {
    int i = blockIdx.x * blockDim.x + threadIdx.x;
    int stride = gridDim.x * blockDim.x;
    const float4* xv = (const float4*)x;
    for (; i < n4; i += stride) {
        float4 v = xv[i];
        half4v h;
        h[0] = (_Float16)v.x; h[1] = (_Float16)v.y;
        h[2] = (_Float16)v.z; h[3] = (_Float16)v.w;
        *(half4v*)(x16 + (size_t)i * 4) = h;
    }
}

// W[K][N] (N=2048) -> WT[N][K], fp32 -> fp16
__global__ void transpose_w(const float* __restrict__ W, _Float16* __restrict__ WT, int K) {
    int id = blockIdx.x * blockDim.x + threadIdx.x;
    int total = K * G4H, stride = gridDim.x * blockDim.x;
    for (; id < total; id += stride) {
        int k = id >> 11;         // /2048
        int n = id & 2047;
        WT[(size_t)n * K + k] = (_Float16)W[id];  // coalesced read over n
    }
}

__global__ void init_state(unsigned* __restrict__ hbuf_u, unsigned* __restrict__ ctr) {
    int id = blockIdx.x * blockDim.x + threadIdx.x;
    if (id < 32768) hbuf_u[id] = 0u;   // zero both h buffers (2*64*512 fp16 = 32768 u32)
    if (id < 128)   ctr[id] = 0u;
}

// ---------- phase 1: xW = x16 @ Wi + (bias in epilogue), fp16 out ----------
__global__ __launch_bounds__(256) void gemm_xw(const _Float16* __restrict__ A,
                                               const _Float16* __restrict__ Bt,
                                               const float* __restrict__ bias,
                                               _Float16* __restrict__ C) {
    __shared__ __align__(16) _Float16 As[128 * 32];
    __shared__ __align__(16) _Float16 Bs[128 * 32];
    const int tid  = threadIdx.x;
    const int w    = tid >> 6;
    const int l    = tid & 63;
    const int lo   = l & 15;
    const int quad = l >> 4;
    const int rowBase = blockIdx.y * 128;
    const int colBase = blockIdx.x * 128;
    const int wr = (w >> 1) * 64, wc = (w & 1) * 64;

    f32x4 acc[4][4] = {};

    const int v0 = tid, v1 = tid + 256;   // vec ids: row = v>>2, kcol = (v&3)*8
    for (int kt = 0; kt < 8; kt++) {
        ((half8*)As)[v0] = *(const half8*)(A + (size_t)(rowBase + (v0 >> 2)) * INSZ + kt * 32 + (v0 & 3) * 8);
        ((half8*)As)[v1] = *(const half8*)(A + (size_t)(rowBase + (v1 >> 2)) * INSZ + kt * 32 + (v1 & 3) * 8);
        ((half8*)Bs)[v0] = *(const half8*)(Bt + (size_t)(colBase + (v0 >> 2)) * INSZ + kt * 32 + (v0 & 3) * 8);
        ((half8*)Bs)[v1] = *(const half8*)(Bt + (size_t)(colBase + (v1 >> 2)) * INSZ + kt * 32 + (v1 & 3) * 8);
        __syncthreads();
        half8 af[4], bf[4];
#pragma unroll
        for (int mt = 0; mt < 4; mt++)
            af[mt] = *(const half8*)(As + (wr + mt * 16 + lo) * 32 + quad * 8);
#pragma unroll
        for (int nt = 0; nt < 4; nt++)
            bf[nt] = *(const half8*)(Bs + (wc + nt * 16 + lo) * 32 + quad * 8);
#pragma unroll
        for (int mt = 0; mt < 4; mt++)
#pragma unroll
            for (int nt = 0; nt < 4; nt++)
                acc[mt][nt] = __builtin_amdgcn_mfma_f32_16x16x32_f16(af[mt], bf[nt], acc[mt][nt], 0, 0, 0);
        __syncthreads();
    }

#pragma unroll
    for (int nt = 0; nt < 4; nt++) {
        int col = colBase + wc + nt * 16 + lo;
        float bv = bias[col];
#pragma unroll
        for (int mt = 0; mt < 4; mt++) {
#pragma unroll
            for (int r = 0; r < 4; r++) {
                int row = rowBase + wr + mt * 16 + quad * 4 + r;
                C[(size_t)row * G4H + col] = (_Float16)(acc[mt][nt][r] + bv);
            }
        }
    }
}

// ---------- phase 2: persistent recurrent scan ----------
// 32 blocks = 4 sample-groups (16 samples) x 8 col-blocks (64 h-cols).
// Wh: gates i,f (q=0,1) register-resident (128 VGPR), gates g,o (q=2,3) in
// fragment-packed LDS (128 KB; each lane stages/reads only its own 512 B, so
// no barrier, no bank conflicts, immune to the per-step buffer_inv).
#define CBLK 8
__global__ __launch_bounds__(256, 1) void lstm_scan(const _Float16* __restrict__ xw,   // [T][64][2048]
                                                    const _Float16* __restrict__ whT,  // [2048][512]
                                                    _Float16* __restrict__ hbuf,       // [2][64][512]
                                                    unsigned* __restrict__ ctr,
                                                    float* __restrict__ out) {
    __shared__ __align__(16) _Float16 ldsW[2 * 16 * 256 * 8];   // 128 KB
    half8* ldsF = (half8*)ldsW;

    const int tid  = threadIdx.x;
    const int w    = tid >> 6;
    const int l    = tid & 63;
    const int lo   = l & 15;
    const int quad = l >> 4;
    const int g = blockIdx.x & 3;
    const int j = blockIdx.x >> 2;
    const int col = j * 64 + w * 16 + lo;   // h column (B n-index / C col)
    const int sr0 = quad * 4;               // C-layout sample-row base
    const int bglob = g * 16;               // first sample of group

    // gates q=2,3 -> LDS (lane-private fragment slots, loaded once)
#pragma unroll
    for (int qq = 0; qq < 2; qq++) {
        const _Float16* wrow = whT + (size_t)((qq + 2) * HSZ + col) * HSZ + quad * 8;
#pragma unroll
        for (int kt = 0; kt < 16; kt++)
            ldsF[(qq * 16 + kt) * 256 + tid] = *(const half8*)(wrow + kt * 32);
    }

    // gates q=0,1 -> registers (128 VGPRs)
    half8 bfrag[2][16];
#pragma unroll
    for (int q = 0; q < 2; q++) {
        const _Float16* wrow = whT + (size_t)(q * HSZ + col) * HSZ + quad * 8;
#pragma unroll
        for (int kt = 0; kt < 16; kt++)
            bfrag[q][kt] = *(const half8*)(wrow + kt * 32);
    }

    float creg[4] = {0.f, 0.f, 0.f, 0.f};

    // prefetch xW for t=0
    float xpre[4][4];
#pragma unroll
    for (int q = 0; q < 4; q++)
#pragma unroll
        for (int r = 0; r < 4; r++)
            xpre[q][r] = (float)xw[(size_t)(bglob + sr0 + r) * G4H + q * HSZ + col];

    unsigned* myctr = ctr + g * 32;

    for (int t = 0; t < T_LEN; t++) {
        const int rb = t & 1, wb = rb ^ 1;

        // A fragments: h_prev[m=lo][k], 16 independent dwordx4 loads (LLC after inv)
        const _Float16* hrow = hbuf + rb * (BSZ * HSZ) + (size_t)(bglob + lo) * HSZ + quad * 8;
        half8 af[16];
#pragma unroll
        for (int kt = 0; kt < 16; kt++) af[kt] = *(const half8*)(hrow + kt * 32);

        f32x4 acc[4];
#pragma unroll
        for (int q = 0; q < 4; q++) {
            acc[q][0] = xpre[q][0]; acc[q][1] = xpre[q][1];
            acc[q][2] = xpre[q][2]; acc[q][3] = xpre[q][3];
        }
#pragma unroll
        for (int kt = 0; kt < 16; kt++) {
            acc[0] = __builtin_amdgcn_mfma_f32_16x16x32_f16(af[kt], bfrag[0][kt], acc[0], 0, 0, 0);
            acc[1] = __builtin_amdgcn_mfma_f32_16x16x32_f16(af[kt], bfrag[1][kt], acc[1], 0, 0, 0);
            half8 b2 = ldsF[kt * 256 + tid];
            half8 b3 = ldsF[(16 + kt) * 256 + tid];
            acc[2] = __builtin_amdgcn_mfma_f32_16x16x32_f16(af[kt], b2, acc[2], 0, 0, 0);
            acc[3] = __builtin_amdgcn_mfma_f32_16x16x32_f16(af[kt], b3, acc[3], 0, 0, 0);
        }

        // prefetch next step's xW (independent of recurrence; overlaps MFMA drain)
        if (t + 1 < T_LEN) {
#pragma unroll
            for (int q = 0; q < 4; q++)
#pragma unroll
                for (int r = 0; r < 4; r++)
                    xpre[q][r] = (float)xw[((size_t)(t + 1) * BSZ + bglob + sr0 + r) * G4H + q * HSZ + col];
        }

        // epilogue: gates -> c,h. h store plain (flushed by wbl2); out stores
        // non-temporal so they don't dirty L2 (keeps the release wbl2 cheap).
#pragma unroll
        for (int r = 0; r < 4; r++) {
            float iv = sigm(acc[0][r]);
            float fv = sigm(acc[1][r]);
            float gv = tanhf_(acc[2][r]);
            float ov = sigm(acc[3][r]);
            float cn = fv * creg[r] + iv * gv;
            creg[r] = cn;
            float hn = ov * tanhf_(cn);
            const size_t brow = (size_t)(bglob + sr0 + r);
            hbuf[wb * (BSZ * HSZ) + brow * HSZ + col] = (_Float16)hn;
            __builtin_nontemporal_store(hn, out + ((size_t)t * BSZ + brow) * HSZ + col);
            if (t == T_LEN - 1) {
                __builtin_nontemporal_store(hn, out + (size_t)T_LEN * BSZ * HSZ + brow * HSZ + col);                        // hT
                __builtin_nontemporal_store(cn, out + (size_t)T_LEN * BSZ * HSZ + (size_t)BSZ * HSZ + brow * HSZ + col);    // cT
            }
        }

        // inter-block barrier (group-local): release wbl2 -> add -> spin -> acquire inv
        __syncthreads();
        if (tid == 0) {
            __threadfence();  // release
            __hip_atomic_fetch_add(myctr, 1u, __ATOMIC_RELAXED, __HIP_MEMORY_SCOPE_AGENT);
            const unsigned target = (unsigned)(CBLK * (t + 1));
            while (__hip_atomic_load(myctr, __ATOMIC_RELAXED, __HIP_MEMORY_SCOPE_AGENT) < target)
                ;
            __threadfence();  // acquire
        }
        __syncthreads();
    }
}

extern "C" void kernel_launch(void* const* d_in, const int* in_sizes, int n_in,
                              void* d_out, int out_size, void* d_ws, size_t ws_size,
                              hipStream_t stream) {
    const float* x  = (const float*)d_in[0];   // [2048,64,256]
    const float* Wi = (const float*)d_in[1];   // [256,2048]
    const float* Wh = (const float*)d_in[2];   // [512,2048]
    const float* B  = (const float*)d_in[3];   // [2048]
    float* out = (float*)d_out;

    char* ws = (char*)d_ws;
    _Float16* xW   = (_Float16*)(ws + OFF_XW);
    _Float16* x16  = (_Float16*)(ws + OFF_X16);
    _Float16* WiT  = (_Float16*)(ws + OFF_WIT);
    _Float16* WhT  = (_Float16*)(ws + OFF_WHT);
    _Float16* hbuf = (_Float16*)(ws + OFF_HBUF);
    unsigned* ctr  = (unsigned*)(ws + OFF_CTR);

    hipLaunchKernelGGL(convert_x, dim3(4096), dim3(256), 0, stream, x, x16, 8388608);
    hipLaunchKernelGGL(transpose_w, dim3(512), dim3(256), 0, stream, Wi, WiT, INSZ);
    hipLaunchKernelGGL(transpose_w, dim3(1024), dim3(256), 0, stream, Wh, WhT, HSZ);
    hipLaunchKernelGGL(init_state, dim3(128), dim3(256), 0, stream, (unsigned*)hbuf, ctr);
    hipLaunchKernelGGL(gemm_xw, dim3(16, 1024), dim3(256), 0, stream, x16, WiT, B, xW);
    hipLaunchKernelGGL(lstm_scan, dim3(32), dim3(256), 0, stream, xW, WhT, hbuf, ctr, out);
}